// Round 1
// baseline (194.536 us; speedup 1.0000x reference)
//
#include <hip/hip_runtime.h>

// LocallyConnectedLinear: out[b,h,w,o] = sum_k patch(x)[b,h,w,k] * W[h,w,k,o]
// k = c*9 + kh*3 + kw  (C slowest, per conv_general_dilated_patches NHWC)
// Shapes: x[8,32,32,64] f32, W[30,30,576,64] f32, out[8,30,30,64] f32.
//
// Memory-bound on the 132.7 MB weight stream (zero reuse across locations).
// One block per (h,w); weights read exactly once, 16B/lane coalesced; batch
// reuse (x8) kept in registers; x patch broadcast from LDS.

#define HO 30
#define WO 30
#define HI 32
#define WI 32
#define CI 64
#define CO 64
#define BATCH 8
#define KTOT 576  // 64*3*3

__global__ __launch_bounds__(256) void lc_kernel(const float* __restrict__ x,
                                                 const float* __restrict__ wgt,
                                                 float* __restrict__ out) {
    const int hw = blockIdx.x;          // 0..899
    const int h  = hw / WO;
    const int w  = hw - h * WO;
    const int tid = threadIdx.x;

    // 32 KB shared: first used as xs[8][576] (18 KB), then reused for the
    // 16x8x64 partial-sum reduction (32 KB) after a barrier.
    __shared__ float smem[8192];
    float* xs = smem;

    // ---- Stage x patches into LDS in k-order ----------------------------
    // idx enumerates (b, kh, kw, c) with c fastest -> coalesced global reads.
    // 8*9*64 = 4608 elements, exactly 18 iterations of 256 threads.
    #pragma unroll
    for (int it = 0; it < 18; ++it) {
        int idx = it * 256 + tid;
        int c  = idx & 63;
        int t  = idx >> 6;        // b*9 + kh*3 + kw
        int b  = t / 9;
        int r  = t - b * 9;
        int kh = r / 3;
        int kw = r - kh * 3;
        float v = x[((b * HI + h + kh) * WI + (w + kw)) * CI + c];
        // stride-9 LDS write: 9 coprime with 32 -> conflict-free
        xs[b * KTOT + c * 9 + kh * 3 + kw] = v;
    }
    __syncthreads();

    // ---- Main streaming loop --------------------------------------------
    const int o4 = tid & 15;   // channel quad: channels 4*o4 .. 4*o4+3
    const int kg = tid >> 4;   // k-group 0..15, each owns 36 k values

    const float4* w4 = reinterpret_cast<const float4*>(
                           wgt + (size_t)hw * KTOT * CO) + o4;  // + k*16

    float4 acc[BATCH];
    #pragma unroll
    for (int b = 0; b < BATCH; ++b) acc[b] = make_float4(0.f, 0.f, 0.f, 0.f);

    const int k0base = kg * 36;
    for (int i = 0; i < 9; ++i) {
        const int k0 = k0base + 4 * i;
        // 4 coalesced 16B weight loads (4 consecutive k, 4 channels each)
        float4 w0 = w4[(k0 + 0) * 16];
        float4 w1 = w4[(k0 + 1) * 16];
        float4 w2 = w4[(k0 + 2) * 16];
        float4 w3 = w4[(k0 + 3) * 16];
        #pragma unroll
        for (int b = 0; b < BATCH; ++b) {
            // broadcast ds_read_b128: all 16 lanes of a kg share the address
            float4 xv = *reinterpret_cast<const float4*>(&xs[b * KTOT + k0]);
            acc[b].x = fmaf(xv.x, w0.x, acc[b].x);
            acc[b].y = fmaf(xv.x, w0.y, acc[b].y);
            acc[b].z = fmaf(xv.x, w0.z, acc[b].z);
            acc[b].w = fmaf(xv.x, w0.w, acc[b].w);
            acc[b].x = fmaf(xv.y, w1.x, acc[b].x);
            acc[b].y = fmaf(xv.y, w1.y, acc[b].y);
            acc[b].z = fmaf(xv.y, w1.z, acc[b].z);
            acc[b].w = fmaf(xv.y, w1.w, acc[b].w);
            acc[b].x = fmaf(xv.z, w2.x, acc[b].x);
            acc[b].y = fmaf(xv.z, w2.y, acc[b].y);
            acc[b].z = fmaf(xv.z, w2.z, acc[b].z);
            acc[b].w = fmaf(xv.z, w2.w, acc[b].w);
            acc[b].x = fmaf(xv.w, w3.x, acc[b].x);
            acc[b].y = fmaf(xv.w, w3.y, acc[b].y);
            acc[b].z = fmaf(xv.w, w3.z, acc[b].z);
            acc[b].w = fmaf(xv.w, w3.w, acc[b].w);
        }
    }

    // ---- Reduce the 16 k-groups via LDS ---------------------------------
    __syncthreads();  // xs no longer needed; reuse smem for partials
    float4* p4 = reinterpret_cast<float4*>(smem);  // [kg][b][o4] float4
    #pragma unroll
    for (int b = 0; b < BATCH; ++b) p4[(kg * BATCH + b) * 16 + o4] = acc[b];
    __syncthreads();

    if (tid < 128) {  // one thread per (b, o4) output quad
        int b   = tid >> 4;
        int oo4 = tid & 15;
        float4 s = make_float4(0.f, 0.f, 0.f, 0.f);
        #pragma unroll
        for (int kgi = 0; kgi < 16; ++kgi) {
            float4 v = p4[(kgi * BATCH + b) * 16 + oo4];
            s.x += v.x; s.y += v.y; s.z += v.z; s.w += v.w;
        }
        float* dst = out + (((size_t)b * HO + h) * WO + w) * CO + oo4 * 4;
        *reinterpret_cast<float4*>(dst) = s;
    }
}

extern "C" void kernel_launch(void* const* d_in, const int* in_sizes, int n_in,
                              void* d_out, int out_size, void* d_ws, size_t ws_size,
                              hipStream_t stream) {
    const float* x   = (const float*)d_in[0];
    const float* wgt = (const float*)d_in[1];
    float* out       = (float*)d_out;
    lc_kernel<<<dim3(HO * WO), dim3(256), 0, stream>>>(x, wgt, out);
}